// Round 1
// baseline (89.204 us; speedup 1.0000x reference)
//
#include <hip/hip_runtime.h>
#include <math.h>

#define NCH 384
#define RNK 5
#define NA  32

// ws 4-byte-word layout
#define WS_NUM   0                    // RNK*NCH floats: numerator[r][c]
#define WS_NANW  (RNK*NCH)            // NCH floats: nan weight per channel
#define WS_TOT   (RNK*NCH + NCH)      // 1 float: total weight
#define WS_MIN   (RNK*NCH + NCH + 1)  // 1 uint: encoded global min of lik_data
#define WS_WORDS (RNK*NCH + NCH + 2)

__device__ __forceinline__ bool finitef(float v) {
    // true iff finite: NaN fails the compare, +-inf exceeds the bound
    return fabsf(v) <= 3.402823466e38f;
}

// order-preserving float<->uint encoding for atomicMin
__device__ __forceinline__ unsigned fenc(float f) {
    unsigned u = __float_as_uint(f);
    return (u & 0x80000000u) ? ~u : (u | 0x80000000u);
}
__device__ __forceinline__ float fdec(unsigned u) {
    unsigned b = (u & 0x80000000u) ? (u ^ 0x80000000u) : ~u;
    return __uint_as_float(b);
}

__global__ void init_ws_kernel(unsigned* __restrict__ ws) {
    int i = blockIdx.x * blockDim.x + threadIdx.x;
    if (i < WS_WORDS) ws[i] = (i == WS_MIN) ? 0xFFFFFFFFu : 0u;
}

__global__ __launch_bounds__(256) void accum_kernel(
    const float* __restrict__ feats,     // (n, RNK, NA)
    const int*   __restrict__ channels,  // (n, NA)
    const float* __restrict__ weights,   // (n,)
    float* __restrict__ ws, int n)
{
    __shared__ float s_num[RNK * NCH];
    __shared__ float s_nanw[NCH];
    __shared__ float s_total;
    const int tid = threadIdx.x;
    for (int i = tid; i < RNK * NCH; i += 256) s_num[i] = 0.f;
    for (int i = tid; i < NCH; i += 256) s_nanw[i] = 0.f;
    if (tid == 0) s_total = 0.f;
    __syncthreads();

    const int spike = blockIdx.x * 256 + tid;
    float w = 0.f;
    if (spike < n) w = weights[spike];

    // block-level total weight: wave reduce then one LDS atomic per wave
    float tw = w;
    #pragma unroll
    for (int off = 32; off; off >>= 1) tw += __shfl_down(tw, off);
    if ((tid & 63) == 0) atomicAdd(&s_total, tw);

    if (spike < n) {
        const float* f  = feats    + (size_t)spike * (RNK * NA);
        const int*  chp = channels + (size_t)spike * NA;

        int ch[NA];                       // fully unrolled -> registers
        #pragma unroll
        for (int q = 0; q < NA / 4; ++q) {
            int4 c4 = ((const int4*)chp)[q];
            ch[4*q+0] = c4.x; ch[4*q+1] = c4.y;
            ch[4*q+2] = c4.z; ch[4*q+3] = c4.w;
        }

        // finiteness mask from rank 0 (reference checks features_full[:,0,:])
        unsigned fmask = 0u;
        #pragma unroll
        for (int q = 0; q < NA / 4; ++q) {
            float4 v = ((const float4*)f)[q];
            if (finitef(v.x)) fmask |= 1u << (4*q+0);
            if (finitef(v.y)) fmask |= 1u << (4*q+1);
            if (finitef(v.z)) fmask |= 1u << (4*q+2);
            if (finitef(v.w)) fmask |= 1u << (4*q+3);
        }

        // nan-weight accumulation
        #pragma unroll
        for (int a = 0; a < NA; ++a)
            if (!((fmask >> a) & 1u)) atomicAdd(&s_nanw[ch[a]], w);

        // numerator accumulation, rank by rank (keeps L1 footprint small)
        for (int r = 0; r < RNK; ++r) {
            const float* fr = f + r * NA;
            #pragma unroll
            for (int q = 0; q < NA / 4; ++q) {
                float4 v = ((const float4*)fr)[q];
                float vv[4] = {v.x, v.y, v.z, v.w};
                #pragma unroll
                for (int k = 0; k < 4; ++k) {
                    int a = 4*q + k;
                    if ((fmask >> a) & 1u) {
                        float val = vv[k];
                        if (!finitef(val)) val = 0.f;   // nan_to_num
                        atomicAdd(&s_num[r * NCH + ch[a]], w * val);
                    }
                }
            }
        }
    }
    __syncthreads();

    for (int i = tid; i < RNK * NCH; i += 256) {
        float v = s_num[i];
        if (v != 0.f) atomicAdd(&ws[WS_NUM + i], v);
    }
    for (int i = tid; i < NCH; i += 256) {
        float v = s_nanw[i];
        if (v != 0.f) atomicAdd(&ws[WS_NANW + i], v);
    }
    if (tid == 0) atomicAdd(&ws[WS_TOT], s_total);
}

__global__ void finalize_kernel(const float* __restrict__ ws,
                                float* __restrict__ out) {
    int i = blockIdx.x * blockDim.x + threadIdx.x;
    if (i < RNK * NCH) {
        int c = i % NCH;
        float total = ws[WS_TOT];
        float cnt = total - ws[WS_NANW + c];
        out[i] = ws[WS_NUM + i] / cnt;
    }
}

__global__ void min_reduce_kernel(const float* __restrict__ data, int nnz,
                                  unsigned* __restrict__ minw) {
    float m = 3.402823466e38f;
    for (int i = blockIdx.x * blockDim.x + threadIdx.x; i < nnz;
         i += gridDim.x * blockDim.x)
        m = fminf(m, data[i]);
    #pragma unroll
    for (int off = 32; off; off >>= 1) m = fminf(m, __shfl_down(m, off));
    if ((threadIdx.x & 63) == 0) atomicMin(minw, fenc(m));
}

__global__ void assign_kernel(const int*   __restrict__ rows,
                              const float* __restrict__ data,
                              const unsigned* __restrict__ ws,
                              float* __restrict__ out, int n, int per) {
    int i = blockIdx.x * blockDim.x + threadIdx.x;
    if (i >= n) return;
    float offset = fdec(ws[WS_MIN]) - 1.0f;
    const float* d  = data + (size_t)i * per;
    const int*   rr = rows + (size_t)i * per;
    float best_s = -3.402823466e38f;
    int best_row = 0x7FFFFFFF;
    for (int j = 0; j < per; ++j) {
        float s = d[j] - offset;   // same float32 op as reference's `shifted`
        int r = rr[j];
        if (s > best_s) { best_s = s; best_row = r; }
        else if (s == best_s && r < best_row) best_row = r;
    }
    // column never empty (per entries each) -> sentinel branch unreachable
    out[RNK * NCH + i] = (float)best_row;
}

extern "C" void kernel_launch(void* const* d_in, const int* in_sizes, int n_in,
                              void* d_out, int out_size, void* d_ws, size_t ws_size,
                              hipStream_t stream) {
    const float* feats    = (const float*)d_in[0];
    const int*   channels = (const int*)d_in[1];
    const float* weights  = (const float*)d_in[2];
    const int*   lik_rows = (const int*)d_in[3];
    // d_in[4] = lik_cols: structurally repeat(arange(n), per), not needed
    const float* lik_data = (const float*)d_in[5];

    int n   = in_sizes[2];
    int nnz = in_sizes[3];
    int per = nnz / n;

    float*    out = (float*)d_out;
    unsigned* wsu = (unsigned*)d_ws;
    float*    wsf = (float*)d_ws;

    init_ws_kernel<<<(WS_WORDS + 255) / 256, 256, 0, stream>>>(wsu);
    accum_kernel<<<(n + 255) / 256, 256, 0, stream>>>(feats, channels, weights, wsf, n);
    finalize_kernel<<<(RNK * NCH + 255) / 256, 256, 0, stream>>>(wsf, out);
    min_reduce_kernel<<<256, 256, 0, stream>>>(lik_data, nnz, wsu + WS_MIN);
    assign_kernel<<<(n + 255) / 256, 256, 0, stream>>>(lik_rows, lik_data, wsu, out, n, per);
}